// Round 5
// baseline (1504.451 us; speedup 1.0000x reference)
//
#include <hip/hip_runtime.h>
#include <hip/hip_bf16.h>
#include <cstdint>

#define B_ 16
#define N_ 4096
#define CPTS_ 64
#define M_ 1024
#define K_ 32

using ushort8 = __attribute__((ext_vector_type(8))) unsigned short;

static __device__ __forceinline__ unsigned f2bf(float x){
  unsigned u = __float_as_uint(x);
  return (u + 0x7fffu + ((u >> 16) & 1u)) >> 16;   // RTNE
}
static __device__ __forceinline__ float bf2f(unsigned short u){
  return __uint_as_float(((unsigned)u) << 16);
}

// DPP max step: v = max(v, dpp_shift(v)). Values are >= 0 so 0-fill is identity.
#define DPPMAX(v, ctrl)                                                        \
  do {                                                                         \
    int _t = __builtin_amdgcn_update_dpp(0, __float_as_int(v), (ctrl), 0xf,    \
                                         0xf, true);                           \
    (v) = fmaxf((v), __int_as_float(_t));                                      \
  } while (0)

// ---------------- FPS: one block per batch, sequential argmax chain ---------
// R5: in-wave reduce via DPP (row_shr 1/2/4/8 + row_bcast 15/31, ~50cy) instead
// of 6 dependent ds_swizzle (~700cy). Winner coords tracked in registers with
// static indexing (no LDS fetch on the winner path). Distance arithmetic
// identical to the passing R1-R4 versions (contract off, sub/mul/add order).
__global__ __launch_bounds__(256, 1) void fps_kernel(const float* __restrict__ xyz,
                                                     float* __restrict__ newxyz){
#pragma clang fp contract(off)
  __shared__ float xs[N_], ys[N_], zs[N_];
  __shared__ int inds_s[M_];
  __shared__ unsigned long long sv_[2][4];
  __shared__ float scx[2][4], scy[2][4], scz[2][4];
  const int b = blockIdx.x, tid = threadIdx.x;
  const int lane = tid & 63, wv = tid >> 6;
  const float* xb = xyz + (size_t)b * N_ * 3;
  for (int i = tid; i < N_ * 3; i += 256){
    float v = xb[i];
    int n = i / 3, c = i - n * 3;
    if (c == 0) xs[n] = v; else if (c == 1) ys[n] = v; else zs[n] = v;
  }
  __syncthreads();
  // per-lane points: n = tid*16 + j  (wave w owns [w*1024, w*1024+1024))
  float px[16], py[16], pz[16], md[16];
  #pragma unroll
  for (int j = 0; j < 16; ++j){
    int n = tid * 16 + j;
    px[j] = xs[n]; py[j] = ys[n]; pz[j] = zs[n]; md[j] = 1e10f;
  }
  int far = 0;
  float cx = xs[0], cy = ys[0], cz = zs[0];
  for (int m = 0; m < M_; ++m){
    if (tid == 0) inds_s[m] = far;
    float bv = -1.0f, bx = 0.f, by = 0.f, bz = 0.f; int bj = 0;
    #pragma unroll
    for (int j = 0; j < 16; ++j){
      float dx = px[j] - cx, dy = py[j] - cy, dz = pz[j] - cz;
      float d = dx * dx; d = d + dy * dy; d = d + dz * dz;  // match ref order, no fma
      float nm = fminf(md[j], d);
      md[j] = nm;
      if (nm > bv){ bv = nm; bj = j; bx = px[j]; by = py[j]; bz = pz[j]; }
    }
    // in-wave max via DPP (VALU, no LDS): result in lane 63
    float wm = bv;
    DPPMAX(wm, 0x111);  // row_shr:1
    DPPMAX(wm, 0x112);  // row_shr:2
    DPPMAX(wm, 0x114);  // row_shr:4
    DPPMAX(wm, 0x118);  // row_shr:8
    DPPMAX(wm, 0x142);  // row_bcast:15
    DPPMAX(wm, 0x143);  // row_bcast:31
    const float wmax = __int_as_float(
        __builtin_amdgcn_readlane(__float_as_int(wm), 63));
    // lowest tied lane = smallest n (lane ascending == n ascending per wave)
    unsigned long long tied = __ballot(bv == wmax);
    const int winlane = (int)__builtin_ctzll(tied);
    const int sl = m & 1;
    if (lane == winlane){
      int wn = tid * 16 + bj;
      sv_[sl][wv] = ((unsigned long long)__float_as_uint(wmax) << 32)
                  | (unsigned)(4095 - wn);     // (4095-n): smaller n wins on tie
      scx[sl][wv] = bx; scy[sl][wv] = by; scz[sl][wv] = bz;
    }
    __syncthreads();
    unsigned long long p0 = sv_[sl][0], p1 = sv_[sl][1], p2 = sv_[sl][2], p3 = sv_[sl][3];
    float x0 = scx[sl][0], y0 = scy[sl][0], z0 = scz[sl][0];
    float x1 = scx[sl][1], y1 = scy[sl][1], z1 = scz[sl][1];
    float x2 = scx[sl][2], y2 = scy[sl][2], z2 = scz[sl][2];
    float x3 = scx[sl][3], y3 = scy[sl][3], z3 = scz[sl][3];
    if (p1 > p0){ p0 = p1; x0 = x1; y0 = y1; z0 = z1; }
    if (p3 > p2){ p2 = p3; x2 = x3; y2 = y3; z2 = z3; }
    if (p2 > p0){ p0 = p2; x0 = x2; y0 = y2; z0 = z2; }
    cx = x0; cy = y0; cz = z0;
    far = 4095 - (int)(p0 & 0xffffffffu);
  }
  __syncthreads();
  for (int t = tid; t < M_; t += 256){
    int id = inds_s[t];
    size_t o = ((size_t)b * M_ + t) * 3;
    newxyz[o] = xs[id]; newxyz[o + 1] = ys[id]; newxyz[o + 2] = zs[id];
  }
}

// ---------------- Ball query: one wave per centroid ------------------------
// fmaf chains match XLA's ffp-contract codegen (R2, exact).
__global__ __launch_bounds__(256) void ballq_kernel(const float* __restrict__ xyz,
                                                    const float* __restrict__ newxyz,
                                                    int* __restrict__ gi,
                                                    float* __restrict__ gif){
  const int gw = (blockIdx.x * 256 + threadIdx.x) >> 6;
  const int lane = threadIdx.x & 63;
  const int b = gw >> 10, m = gw & 1023;
  const float* xb = xyz + (size_t)b * N_ * 3;
  const size_t no = (size_t)b * M_ + m;
  const float cx = newxyz[no * 3], cy = newxyz[no * 3 + 1], cz = newxyz[no * 3 + 2];
  const float sm = fmaf(cz, cz, fmaf(cy, cy, cx * cx));
  int total = 0, first_idx = 0; bool havef = false;
  int*   gd = gi  + no * K_;
  float* fd = gif + no * K_;
  for (int ch = 0; ch < 64 && total < K_; ++ch){
    const int n = ch * 64 + lane;
    const float x = xb[n * 3], y = xb[n * 3 + 1], z = xb[n * 3 + 2];
    const float sn = fmaf(z, z, fmaf(y, y, x * x));
    const float dt = fmaf(z, cz, fmaf(y, cy, x * cx));
    float d2 = (sm + sn) - 2.0f * dt;                 // ref: |a|^2+|b|^2-2ab
    float dist = sqrtf(fmaxf(d2, 0.0f));
    bool pred = !(dist > 0.2f);
    unsigned long long mask = __ballot(pred);
    if (!havef && mask){ havef = true; first_idx = ch * 64 + (int)__builtin_ctzll(mask); }
    if (pred){
      int rank = total + (int)__popcll(mask & ((1ull << lane) - 1ull));
      if (rank < K_){ gd[rank] = n; fd[rank] = (float)n; }
    }
    total += (int)__popcll(mask);
  }
  if (total < K_ && lane >= total && lane < K_){ gd[lane] = first_idx; fd[lane] = (float)first_idx; }
}

// ---------------- MLP pass (gather / bn-in, store+stats / stats / maxpool) --
// MIN_: 0 = gather feats from xyz/points, 1 = read h_in (bf16) + BN + ReLU
// MOUT_: 0 = store h (bf16) + partial stats, 1 = partial stats only,
//        2 = BN + ReLU + max-pool over K -> out
template<int CIN, int COUT, int MIN_, int MOUT_>
__global__ __launch_bounds__(256) void mlp_pass(
    const float* __restrict__ xyz, const float* __restrict__ points,
    const float* __restrict__ newxyz, const int* __restrict__ gi,
    const unsigned short* __restrict__ hin, const float* __restrict__ bnin,
    const float* __restrict__ W,
    unsigned short* __restrict__ hout, float* __restrict__ part,
    const float* __restrict__ bncur, float* __restrict__ out)
{
  constexpr int OPT = COUT / 8;
  static_assert(OPT % 4 == 0, "OPT");
  __shared__ __align__(16) float Wt[CIN][COUT];
  __shared__ __align__(16) float ft[CIN][128];
  const int tid = threadIdx.x, blk = blockIdx.x;
  const size_t s0 = (size_t)blk * 128;

  for (int i = tid; i < CIN * COUT; i += 256){
    int o = i / CIN, c = i - o * CIN;
    Wt[c][o] = W[i];
  }

  if constexpr (MIN_ == 0){
    __shared__ int gidx[128];
    __shared__ float nx[4][3];
    const int b  = (int)(s0 >> 15);                 // 32768 samples per batch
    const int m0 = ((int)(s0 & 32767)) >> 5;        // 4 m's per block
    if (tid < 128) gidx[tid] = gi[(size_t)b * 32768 + (size_t)m0 * K_ + tid];
    if (tid < 12){
      int mi = tid / 3, c = tid - mi * 3;
      nx[mi][c] = newxyz[((size_t)b * M_ + m0 + mi) * 3 + c];
    }
    __syncthreads();
    const int sl = tid >> 1, half = tid & 1;
    const int g = gidx[sl];
    const float* ps = points + ((size_t)b * N_ + g) * CPTS_ + half * 32;
    #pragma unroll
    for (int j = 0; j < 8; ++j){
      float4 v = *reinterpret_cast<const float4*>(ps + j * 4);
      int c = 3 + half * 32 + j * 4;
      ft[c][sl] = v.x; ft[c + 1][sl] = v.y; ft[c + 2][sl] = v.z; ft[c + 3][sl] = v.w;
    }
    if (half == 0){
      const float* xp = xyz + ((size_t)b * N_ + g) * 3;
      const int mi = sl >> 5;
      ft[0][sl] = xp[0] - nx[mi][0];
      ft[1][sl] = xp[1] - nx[mi][1];
      ft[2][sl] = xp[2] - nx[mi][2];
    }
  } else {
    const int sl = tid >> 1, c0 = (tid & 1) * 32;
    const unsigned short* hp = hin + (s0 + sl) * CIN + c0;
    #pragma unroll
    for (int j = 0; j < 4; ++j){
      ushort8 raw = *reinterpret_cast<const ushort8*>(hp + j * 8);
      #pragma unroll
      for (int e = 0; e < 8; ++e){
        int c = c0 + j * 8 + e;
        float h = bf2f(raw[e]);
        float f = h * bnin[c] + bnin[CIN + c];
        ft[c][sl] = fmaxf(f, 0.0f);
      }
    }
  }
  __syncthreads();

  const int sg = tid & 31, og = tid >> 5;
  float acc[4][OPT];
  #pragma unroll
  for (int i = 0; i < 4; ++i)
    #pragma unroll
    for (int o = 0; o < OPT; ++o) acc[i][o] = 0.0f;

  #pragma unroll 2
  for (int c = 0; c < CIN; ++c){
    float4 f = *reinterpret_cast<const float4*>(&ft[c][sg * 4]);
    float4 w[OPT / 4];
    #pragma unroll
    for (int j = 0; j < OPT / 4; ++j)
      w[j] = *reinterpret_cast<const float4*>(&Wt[c][og * OPT + j * 4]);
    const float fv[4] = {f.x, f.y, f.z, f.w};
    #pragma unroll
    for (int i = 0; i < 4; ++i){
      #pragma unroll
      for (int j = 0; j < OPT / 4; ++j){
        acc[i][j * 4 + 0] += fv[i] * w[j].x;
        acc[i][j * 4 + 1] += fv[i] * w[j].y;
        acc[i][j * 4 + 2] += fv[i] * w[j].z;
        acc[i][j * 4 + 3] += fv[i] * w[j].w;
      }
    }
  }

  if constexpr (MOUT_ == 0 || MOUT_ == 1){
    if constexpr (MOUT_ == 0){
      #pragma unroll
      for (int i = 0; i < 4; ++i){
        size_t s = s0 + sg * 4 + i;
        unsigned pk[OPT / 2];
        #pragma unroll
        for (int o = 0; o < OPT / 2; ++o)
          pk[o] = f2bf(acc[i][2 * o]) | (f2bf(acc[i][2 * o + 1]) << 16);
        uint4* dst = reinterpret_cast<uint4*>(hout + s * COUT + og * OPT);
        dst[0] = make_uint4(pk[0], pk[1], pk[2], pk[3]);
        if constexpr (OPT == 16) dst[1] = make_uint4(pk[4], pk[5], pk[6], pk[7]);
      }
    }
    float sv[OPT], sq[OPT];
    #pragma unroll
    for (int o = 0; o < OPT; ++o){
      float a0 = acc[0][o], a1 = acc[1][o], a2 = acc[2][o], a3 = acc[3][o];
      sv[o] = ((a0 + a1) + a2) + a3;
      sq[o] = ((a0 * a0 + a1 * a1) + a2 * a2) + a3 * a3;
    }
    #pragma unroll
    for (int off = 1; off < 32; off <<= 1){
      #pragma unroll
      for (int o = 0; o < OPT; ++o){
        sv[o] += __shfl_xor(sv[o], off);
        sq[o] += __shfl_xor(sq[o], off);
      }
    }
    if (sg == 0){
      #pragma unroll
      for (int o = 0; o < OPT; ++o){
        int ch = og * OPT + o;
        part[(size_t)(ch * 2) * 4096 + blk]     = sv[o];
        part[(size_t)(ch * 2 + 1) * 4096 + blk] = sq[o];
      }
    }
  } else {
    const int mloc = sg >> 3;
    float mx[OPT];
    #pragma unroll
    for (int o = 0; o < OPT; ++o){
      int ch = og * OPT + o;
      float a = bncur[ch], sh = bncur[COUT + ch];
      float v0 = fmaxf(acc[0][o] * a + sh, 0.0f);
      float v1 = fmaxf(acc[1][o] * a + sh, 0.0f);
      float v2 = fmaxf(acc[2][o] * a + sh, 0.0f);
      float v3 = fmaxf(acc[3][o] * a + sh, 0.0f);
      mx[o] = fmaxf(fmaxf(v0, v1), fmaxf(v2, v3));
    }
    #pragma unroll
    for (int off = 1; off < 8; off <<= 1)
      #pragma unroll
      for (int o = 0; o < OPT; ++o)
        mx[o] = fmaxf(mx[o], __shfl_xor(mx[o], off));
    if ((sg & 7) == 0){
      size_t mf = (s0 >> 5) + mloc;
      float* dst = out + mf * COUT + og * OPT;
      #pragma unroll
      for (int j = 0; j < OPT / 4; ++j)
        *reinterpret_cast<float4*>(dst + j * 4) =
            make_float4(mx[j * 4], mx[j * 4 + 1], mx[j * 4 + 2], mx[j * 4 + 3]);
    }
  }
}

// ---------------- BN stats reduce + scale/shift -----------------------------
__global__ __launch_bounds__(256) void reduce_stats(const float* __restrict__ part,
                                                    const float* __restrict__ g,
                                                    const float* __restrict__ bb,
                                                    float* __restrict__ bn, int cout){
  const int ch = blockIdx.x, tid = threadIdx.x;
  float s = 0.f, q = 0.f;
  const float* ps = part + (size_t)(ch * 2) * 4096;
  const float* pq = part + (size_t)(ch * 2 + 1) * 4096;
  for (int i = tid; i < 4096; i += 256){ s += ps[i]; q += pq[i]; }
  #pragma unroll
  for (int off = 1; off < 64; off <<= 1){ s += __shfl_xor(s, off); q += __shfl_xor(q, off); }
  __shared__ float as_[4], aq_[4];
  if ((tid & 63) == 0){ as_[tid >> 6] = s; aq_[tid >> 6] = q; }
  __syncthreads();
  if (tid == 0){
    float S = as_[0] + as_[1] + as_[2] + as_[3];
    float Q = aq_[0] + aq_[1] + aq_[2] + aq_[3];
    const float cnt = 524288.0f;
    float mean = S / cnt;
    float var  = Q / cnt - mean * mean;
    float sc = g[ch] / sqrtf(var + 1e-5f);
    bn[ch] = sc;
    bn[cout + ch] = bb[ch] - mean * sc;
  }
}

// ---------------- Max-pool from stored h2 (full-ws path) --------------------
__global__ __launch_bounds__(128) void maxpool_kernel(const unsigned short* __restrict__ h2,
                                                      const float* __restrict__ bn2,
                                                      float* __restrict__ out){
  const int mf = blockIdx.x, ch = threadIdx.x;
  const float a = bn2[ch], sh = bn2[128 + ch];
  const unsigned short* hp = h2 + (size_t)mf * 32 * 128 + ch;
  float mx = 0.0f;                       // ReLU outputs are >= 0
  #pragma unroll 8
  for (int k = 0; k < 32; ++k){
    float v = bf2f(hp[(size_t)k * 128]);
    mx = fmaxf(mx, fmaxf(v * a + sh, 0.0f));
  }
  out[(size_t)mf * 128 + ch] = mx;
}

extern "C" void kernel_launch(void* const* d_in, const int* in_sizes, int n_in,
                              void* d_out, int out_size, void* d_ws, size_t ws_size,
                              hipStream_t stream){
  (void)in_sizes; (void)n_in; (void)out_size;
  const float* xyz    = (const float*)d_in[0];
  const float* points = (const float*)d_in[1];
  const float* W0 = (const float*)d_in[2];
  const float* g0 = (const float*)d_in[3];
  const float* b0 = (const float*)d_in[4];
  const float* W1 = (const float*)d_in[5];
  const float* g1 = (const float*)d_in[6];
  const float* b1 = (const float*)d_in[7];
  const float* W2 = (const float*)d_in[8];
  const float* g2 = (const float*)d_in[9];
  const float* b2 = (const float*)d_in[10];

  float* out = (float*)d_out;
  float* o_newxyz = out;
  float* o_newpts = out + (size_t)B_ * M_ * 3;
  float* o_gind   = out + (size_t)B_ * M_ * 3 + (size_t)B_ * M_ * 128;

  char* ws = (char*)d_ws;
  int*   gi   = (int*)(ws + 0);                         // 2 MB
  float* part = (float*)(ws + (2u << 20));              // 4 MB
  float* bn0  = (float*)(ws + (6u << 20));
  float* bn1  = (float*)(ws + (6u << 20) + 1024);
  float* bn2  = (float*)(ws + (6u << 20) + 2048);
  unsigned short* h0 = (unsigned short*)(ws + (8u << 20));                    // 64 MB
  unsigned short* h1 = (unsigned short*)(ws + (8u << 20) + 67108864ull);      // 64 MB
  unsigned short* h2 = (unsigned short*)(ws + (8u << 20) + 2ull * 67108864ull); // 128 MB
  const bool full = ws_size >= ((8ull << 20) + 2ull * 67108864ull + 134217728ull);

  fps_kernel<<<16, 256, 0, stream>>>(xyz, o_newxyz);
  ballq_kernel<<<4096, 256, 0, stream>>>(xyz, o_newxyz, gi, o_gind);

  mlp_pass<67, 64, 0, 0><<<4096, 256, 0, stream>>>(xyz, points, o_newxyz, gi,
      nullptr, nullptr, W0, h0, part, nullptr, nullptr);
  reduce_stats<<<64, 256, 0, stream>>>(part, g0, b0, bn0, 64);

  mlp_pass<64, 64, 1, 0><<<4096, 256, 0, stream>>>(xyz, points, o_newxyz, gi,
      h0, bn0, W1, h1, part, nullptr, nullptr);
  reduce_stats<<<64, 256, 0, stream>>>(part, g1, b1, bn1, 64);

  if (full){
    mlp_pass<64, 128, 1, 0><<<4096, 256, 0, stream>>>(xyz, points, o_newxyz, gi,
        h1, bn1, W2, h2, part, nullptr, nullptr);
    reduce_stats<<<128, 256, 0, stream>>>(part, g2, b2, bn2, 128);
    maxpool_kernel<<<16384, 128, 0, stream>>>(h2, bn2, o_newpts);
  } else {
    mlp_pass<64, 128, 1, 1><<<4096, 256, 0, stream>>>(xyz, points, o_newxyz, gi,
        h1, bn1, W2, nullptr, part, nullptr, nullptr);
    reduce_stats<<<128, 256, 0, stream>>>(part, g2, b2, bn2, 128);
    mlp_pass<64, 128, 1, 2><<<4096, 256, 0, stream>>>(xyz, points, o_newxyz, gi,
        h1, bn1, W2, nullptr, nullptr, bn2, o_newpts);
  }
}

// Round 6
// 1275.009 us; speedup vs baseline: 1.1800x; 1.1800x over previous
//
#include <hip/hip_runtime.h>
#include <hip/hip_bf16.h>
#include <cstdint>

#define B_ 16
#define N_ 4096
#define CPTS_ 64
#define M_ 1024
#define K_ 32

using ushort8 = __attribute__((ext_vector_type(8))) unsigned short;

static __device__ __forceinline__ unsigned f2bf(float x){
  unsigned u = __float_as_uint(x);
  return (u + 0x7fffu + ((u >> 16) & 1u)) >> 16;   // RTNE
}
static __device__ __forceinline__ float bf2f(unsigned short u){
  return __uint_as_float(((unsigned)u) << 16);
}

// DPP max step: v = max(v, dpp_shift(v)). Values are >= 0 so 0-fill is identity.
#define DPPMAX(v, ctrl)                                                        \
  do {                                                                         \
    int _t = __builtin_amdgcn_update_dpp(0, __float_as_int(v), (ctrl), 0xf,    \
                                         0xf, true);                           \
    (v) = fmaxf((v), __int_as_float(_t));                                      \
  } while (0)

// One distance update, all indices compile-time constant (named float4 comps).
// Arithmetic identical to the passing R1-R5 versions (contract off, order kept).
#define STEP(MD, PX, PY, PZ, C, J)                                             \
  { float dx = PX.C - cx, dy = PY.C - cy, dz = PZ.C - cz;                      \
    float d = dx * dx; d = d + dy * dy; d = d + dz * dz;                       \
    float nm = fminf(MD.C, d); MD.C = nm;                                      \
    if (nm > bv){ bv = nm; bj = (J); } }
#define STEP4(MD, PX, PY, PZ, J0)                                              \
  STEP(MD, PX, PY, PZ, x, J0)                                                  \
  STEP(MD, PX, PY, PZ, y, (J0) + 1)                                            \
  STEP(MD, PX, PY, PZ, z, (J0) + 2)                                            \
  STEP(MD, PX, PY, PZ, w, (J0) + 3)

// ---------------- FPS: one block per batch, sequential argmax chain ---------
// R6: named float4s + constant-index expansion to FORCE register residency
// (R3-R5 showed VGPR=68 < the 84+ needed -> compiler kept the j-loop rolled
// with movrel-style indexed access, ~2x VALU issue). Winner path = R4 style
// (piggyback coords via winner lane, no per-step coord cndmasks).
__global__ __launch_bounds__(256, 1) void fps_kernel(const float* __restrict__ xyz,
                                                     float* __restrict__ newxyz){
#pragma clang fp contract(off)
  __shared__ float xs[N_], ys[N_], zs[N_];
  __shared__ int inds_s[M_];
  __shared__ unsigned long long sv_[2][4];
  __shared__ float scx[2][4], scy[2][4], scz[2][4];
  const int b = blockIdx.x, tid = threadIdx.x;
  const int lane = tid & 63, wv = tid >> 6;
  const float* xb = xyz + (size_t)b * N_ * 3;
  for (int i = tid; i < N_ * 3; i += 256){
    float v = xb[i];
    int n = i / 3, c = i - n * 3;
    if (c == 0) xs[n] = v; else if (c == 1) ys[n] = v; else zs[n] = v;
  }
  __syncthreads();
  // per-lane points: n = tid*16 + j  (wave w owns [w*1024, w*1024+1024))
  const float4 px0 = *reinterpret_cast<const float4*>(&xs[tid * 16 + 0]);
  const float4 px1 = *reinterpret_cast<const float4*>(&xs[tid * 16 + 4]);
  const float4 px2 = *reinterpret_cast<const float4*>(&xs[tid * 16 + 8]);
  const float4 px3 = *reinterpret_cast<const float4*>(&xs[tid * 16 + 12]);
  const float4 py0 = *reinterpret_cast<const float4*>(&ys[tid * 16 + 0]);
  const float4 py1 = *reinterpret_cast<const float4*>(&ys[tid * 16 + 4]);
  const float4 py2 = *reinterpret_cast<const float4*>(&ys[tid * 16 + 8]);
  const float4 py3 = *reinterpret_cast<const float4*>(&ys[tid * 16 + 12]);
  const float4 pz0 = *reinterpret_cast<const float4*>(&zs[tid * 16 + 0]);
  const float4 pz1 = *reinterpret_cast<const float4*>(&zs[tid * 16 + 4]);
  const float4 pz2 = *reinterpret_cast<const float4*>(&zs[tid * 16 + 8]);
  const float4 pz3 = *reinterpret_cast<const float4*>(&zs[tid * 16 + 12]);
  float4 md0 = make_float4(1e10f, 1e10f, 1e10f, 1e10f);
  float4 md1 = md0, md2 = md0, md3 = md0;
  int far = 0;
  float cx = xs[0], cy = ys[0], cz = zs[0];
  for (int m = 0; m < M_; ++m){
    if (tid == 0) inds_s[m] = far;
    float bv = -1.0f; int bj = 0;
    STEP4(md0, px0, py0, pz0, 0)
    STEP4(md1, px1, py1, pz1, 4)
    STEP4(md2, px2, py2, pz2, 8)
    STEP4(md3, px3, py3, pz3, 12)
    // in-wave max via DPP (VALU, no LDS): result in lane 63
    float wm = bv;
    DPPMAX(wm, 0x111);  // row_shr:1
    DPPMAX(wm, 0x112);  // row_shr:2
    DPPMAX(wm, 0x114);  // row_shr:4
    DPPMAX(wm, 0x118);  // row_shr:8
    DPPMAX(wm, 0x142);  // row_bcast:15
    DPPMAX(wm, 0x143);  // row_bcast:31
    const float wmax = __int_as_float(
        __builtin_amdgcn_readlane(__float_as_int(wm), 63));
    // lowest tied lane = smallest n (lane ascending == n ascending per wave)
    unsigned long long tied = __ballot(bv == wmax);
    const int winlane = (int)__builtin_ctzll(tied);
    const int sl = m & 1;
    if (lane == winlane){
      int wn = tid * 16 + bj;
      sv_[sl][wv] = ((unsigned long long)__float_as_uint(wmax) << 32)
                  | (unsigned)(4095 - wn);     // (4095-n): smaller n wins on tie
      scx[sl][wv] = xs[wn]; scy[sl][wv] = ys[wn]; scz[sl][wv] = zs[wn];
    }
    __syncthreads();
    unsigned long long p0 = sv_[sl][0], p1 = sv_[sl][1], p2 = sv_[sl][2], p3 = sv_[sl][3];
    float x0 = scx[sl][0], y0 = scy[sl][0], z0 = scz[sl][0];
    float x1 = scx[sl][1], y1 = scy[sl][1], z1 = scz[sl][1];
    float x2 = scx[sl][2], y2 = scy[sl][2], z2 = scz[sl][2];
    float x3 = scx[sl][3], y3 = scy[sl][3], z3 = scz[sl][3];
    if (p1 > p0){ p0 = p1; x0 = x1; y0 = y1; z0 = z1; }
    if (p3 > p2){ p2 = p3; x2 = x3; y2 = y3; z2 = z3; }
    if (p2 > p0){ p0 = p2; x0 = x2; y0 = y2; z0 = z2; }
    cx = x0; cy = y0; cz = z0;
    far = 4095 - (int)(p0 & 0xffffffffu);
  }
  __syncthreads();
  for (int t = tid; t < M_; t += 256){
    int id = inds_s[t];
    size_t o = ((size_t)b * M_ + t) * 3;
    newxyz[o] = xs[id]; newxyz[o + 1] = ys[id]; newxyz[o + 2] = zs[id];
  }
}

// ---------------- Ball query: one wave per centroid ------------------------
// fmaf chains match XLA's ffp-contract codegen (R2, exact).
__global__ __launch_bounds__(256) void ballq_kernel(const float* __restrict__ xyz,
                                                    const float* __restrict__ newxyz,
                                                    int* __restrict__ gi,
                                                    float* __restrict__ gif){
  const int gw = (blockIdx.x * 256 + threadIdx.x) >> 6;
  const int lane = threadIdx.x & 63;
  const int b = gw >> 10, m = gw & 1023;
  const float* xb = xyz + (size_t)b * N_ * 3;
  const size_t no = (size_t)b * M_ + m;
  const float cx = newxyz[no * 3], cy = newxyz[no * 3 + 1], cz = newxyz[no * 3 + 2];
  const float sm = fmaf(cz, cz, fmaf(cy, cy, cx * cx));
  int total = 0, first_idx = 0; bool havef = false;
  int*   gd = gi  + no * K_;
  float* fd = gif + no * K_;
  for (int ch = 0; ch < 64 && total < K_; ++ch){
    const int n = ch * 64 + lane;
    const float x = xb[n * 3], y = xb[n * 3 + 1], z = xb[n * 3 + 2];
    const float sn = fmaf(z, z, fmaf(y, y, x * x));
    const float dt = fmaf(z, cz, fmaf(y, cy, x * cx));
    float d2 = (sm + sn) - 2.0f * dt;                 // ref: |a|^2+|b|^2-2ab
    float dist = sqrtf(fmaxf(d2, 0.0f));
    bool pred = !(dist > 0.2f);
    unsigned long long mask = __ballot(pred);
    if (!havef && mask){ havef = true; first_idx = ch * 64 + (int)__builtin_ctzll(mask); }
    if (pred){
      int rank = total + (int)__popcll(mask & ((1ull << lane) - 1ull));
      if (rank < K_){ gd[rank] = n; fd[rank] = (float)n; }
    }
    total += (int)__popcll(mask);
  }
  if (total < K_ && lane >= total && lane < K_){ gd[lane] = first_idx; fd[lane] = (float)first_idx; }
}

// ---------------- MLP pass (gather / bn-in, store+stats / stats / maxpool) --
// MIN_: 0 = gather feats from xyz/points, 1 = read h_in (bf16) + BN + ReLU
// MOUT_: 0 = store h (bf16) + partial stats, 1 = partial stats only,
//        2 = BN + ReLU + max-pool over K -> out
template<int CIN, int COUT, int MIN_, int MOUT_>
__global__ __launch_bounds__(256) void mlp_pass(
    const float* __restrict__ xyz, const float* __restrict__ points,
    const float* __restrict__ newxyz, const int* __restrict__ gi,
    const unsigned short* __restrict__ hin, const float* __restrict__ bnin,
    const float* __restrict__ W,
    unsigned short* __restrict__ hout, float* __restrict__ part,
    const float* __restrict__ bncur, float* __restrict__ out)
{
  constexpr int OPT = COUT / 8;
  static_assert(OPT % 4 == 0, "OPT");
  __shared__ __align__(16) float Wt[CIN][COUT];
  __shared__ __align__(16) float ft[CIN][128];
  const int tid = threadIdx.x, blk = blockIdx.x;
  const size_t s0 = (size_t)blk * 128;

  for (int i = tid; i < CIN * COUT; i += 256){
    int o = i / CIN, c = i - o * CIN;
    Wt[c][o] = W[i];
  }

  if constexpr (MIN_ == 0){
    __shared__ int gidx[128];
    __shared__ float nx[4][3];
    const int b  = (int)(s0 >> 15);                 // 32768 samples per batch
    const int m0 = ((int)(s0 & 32767)) >> 5;        // 4 m's per block
    if (tid < 128) gidx[tid] = gi[(size_t)b * 32768 + (size_t)m0 * K_ + tid];
    if (tid < 12){
      int mi = tid / 3, c = tid - mi * 3;
      nx[mi][c] = newxyz[((size_t)b * M_ + m0 + mi) * 3 + c];
    }
    __syncthreads();
    const int sl = tid >> 1, half = tid & 1;
    const int g = gidx[sl];
    const float* ps = points + ((size_t)b * N_ + g) * CPTS_ + half * 32;
    #pragma unroll
    for (int j = 0; j < 8; ++j){
      float4 v = *reinterpret_cast<const float4*>(ps + j * 4);
      int c = 3 + half * 32 + j * 4;
      ft[c][sl] = v.x; ft[c + 1][sl] = v.y; ft[c + 2][sl] = v.z; ft[c + 3][sl] = v.w;
    }
    if (half == 0){
      const float* xp = xyz + ((size_t)b * N_ + g) * 3;
      const int mi = sl >> 5;
      ft[0][sl] = xp[0] - nx[mi][0];
      ft[1][sl] = xp[1] - nx[mi][1];
      ft[2][sl] = xp[2] - nx[mi][2];
    }
  } else {
    const int sl = tid >> 1, c0 = (tid & 1) * 32;
    const unsigned short* hp = hin + (s0 + sl) * CIN + c0;
    #pragma unroll
    for (int j = 0; j < 4; ++j){
      ushort8 raw = *reinterpret_cast<const ushort8*>(hp + j * 8);
      #pragma unroll
      for (int e = 0; e < 8; ++e){
        int c = c0 + j * 8 + e;
        float h = bf2f(raw[e]);
        float f = h * bnin[c] + bnin[CIN + c];
        ft[c][sl] = fmaxf(f, 0.0f);
      }
    }
  }
  __syncthreads();

  const int sg = tid & 31, og = tid >> 5;
  float acc[4][OPT];
  #pragma unroll
  for (int i = 0; i < 4; ++i)
    #pragma unroll
    for (int o = 0; o < OPT; ++o) acc[i][o] = 0.0f;

  #pragma unroll 2
  for (int c = 0; c < CIN; ++c){
    float4 f = *reinterpret_cast<const float4*>(&ft[c][sg * 4]);
    float4 w[OPT / 4];
    #pragma unroll
    for (int j = 0; j < OPT / 4; ++j)
      w[j] = *reinterpret_cast<const float4*>(&Wt[c][og * OPT + j * 4]);
    const float fv[4] = {f.x, f.y, f.z, f.w};
    #pragma unroll
    for (int i = 0; i < 4; ++i){
      #pragma unroll
      for (int j = 0; j < OPT / 4; ++j){
        acc[i][j * 4 + 0] += fv[i] * w[j].x;
        acc[i][j * 4 + 1] += fv[i] * w[j].y;
        acc[i][j * 4 + 2] += fv[i] * w[j].z;
        acc[i][j * 4 + 3] += fv[i] * w[j].w;
      }
    }
  }

  if constexpr (MOUT_ == 0 || MOUT_ == 1){
    if constexpr (MOUT_ == 0){
      #pragma unroll
      for (int i = 0; i < 4; ++i){
        size_t s = s0 + sg * 4 + i;
        unsigned pk[OPT / 2];
        #pragma unroll
        for (int o = 0; o < OPT / 2; ++o)
          pk[o] = f2bf(acc[i][2 * o]) | (f2bf(acc[i][2 * o + 1]) << 16);
        uint4* dst = reinterpret_cast<uint4*>(hout + s * COUT + og * OPT);
        dst[0] = make_uint4(pk[0], pk[1], pk[2], pk[3]);
        if constexpr (OPT == 16) dst[1] = make_uint4(pk[4], pk[5], pk[6], pk[7]);
      }
    }
    float sv[OPT], sq[OPT];
    #pragma unroll
    for (int o = 0; o < OPT; ++o){
      float a0 = acc[0][o], a1 = acc[1][o], a2 = acc[2][o], a3 = acc[3][o];
      sv[o] = ((a0 + a1) + a2) + a3;
      sq[o] = ((a0 * a0 + a1 * a1) + a2 * a2) + a3 * a3;
    }
    #pragma unroll
    for (int off = 1; off < 32; off <<= 1){
      #pragma unroll
      for (int o = 0; o < OPT; ++o){
        sv[o] += __shfl_xor(sv[o], off);
        sq[o] += __shfl_xor(sq[o], off);
      }
    }
    if (sg == 0){
      #pragma unroll
      for (int o = 0; o < OPT; ++o){
        int ch = og * OPT + o;
        part[(size_t)(ch * 2) * 4096 + blk]     = sv[o];
        part[(size_t)(ch * 2 + 1) * 4096 + blk] = sq[o];
      }
    }
  } else {
    const int mloc = sg >> 3;
    float mx[OPT];
    #pragma unroll
    for (int o = 0; o < OPT; ++o){
      int ch = og * OPT + o;
      float a = bncur[ch], sh = bncur[COUT + ch];
      float v0 = fmaxf(acc[0][o] * a + sh, 0.0f);
      float v1 = fmaxf(acc[1][o] * a + sh, 0.0f);
      float v2 = fmaxf(acc[2][o] * a + sh, 0.0f);
      float v3 = fmaxf(acc[3][o] * a + sh, 0.0f);
      mx[o] = fmaxf(fmaxf(v0, v1), fmaxf(v2, v3));
    }
    #pragma unroll
    for (int off = 1; off < 8; off <<= 1)
      #pragma unroll
      for (int o = 0; o < OPT; ++o)
        mx[o] = fmaxf(mx[o], __shfl_xor(mx[o], off));
    if ((sg & 7) == 0){
      size_t mf = (s0 >> 5) + mloc;
      float* dst = out + mf * COUT + og * OPT;
      #pragma unroll
      for (int j = 0; j < OPT / 4; ++j)
        *reinterpret_cast<float4*>(dst + j * 4) =
            make_float4(mx[j * 4], mx[j * 4 + 1], mx[j * 4 + 2], mx[j * 4 + 3]);
    }
  }
}

// ---------------- BN stats reduce + scale/shift -----------------------------
__global__ __launch_bounds__(256) void reduce_stats(const float* __restrict__ part,
                                                    const float* __restrict__ g,
                                                    const float* __restrict__ bb,
                                                    float* __restrict__ bn, int cout){
  const int ch = blockIdx.x, tid = threadIdx.x;
  float s = 0.f, q = 0.f;
  const float* ps = part + (size_t)(ch * 2) * 4096;
  const float* pq = part + (size_t)(ch * 2 + 1) * 4096;
  for (int i = tid; i < 4096; i += 256){ s += ps[i]; q += pq[i]; }
  #pragma unroll
  for (int off = 1; off < 64; off <<= 1){ s += __shfl_xor(s, off); q += __shfl_xor(q, off); }
  __shared__ float as_[4], aq_[4];
  if ((tid & 63) == 0){ as_[tid >> 6] = s; aq_[tid >> 6] = q; }
  __syncthreads();
  if (tid == 0){
    float S = as_[0] + as_[1] + as_[2] + as_[3];
    float Q = aq_[0] + aq_[1] + aq_[2] + aq_[3];
    const float cnt = 524288.0f;
    float mean = S / cnt;
    float var  = Q / cnt - mean * mean;
    float sc = g[ch] / sqrtf(var + 1e-5f);
    bn[ch] = sc;
    bn[cout + ch] = bb[ch] - mean * sc;
  }
}

// ---------------- Max-pool from stored h2 (full-ws path) --------------------
__global__ __launch_bounds__(128) void maxpool_kernel(const unsigned short* __restrict__ h2,
                                                      const float* __restrict__ bn2,
                                                      float* __restrict__ out){
  const int mf = blockIdx.x, ch = threadIdx.x;
  const float a = bn2[ch], sh = bn2[128 + ch];
  const unsigned short* hp = h2 + (size_t)mf * 32 * 128 + ch;
  float mx = 0.0f;                       // ReLU outputs are >= 0
  #pragma unroll 8
  for (int k = 0; k < 32; ++k){
    float v = bf2f(hp[(size_t)k * 128]);
    mx = fmaxf(mx, fmaxf(v * a + sh, 0.0f));
  }
  out[(size_t)mf * 128 + ch] = mx;
}

extern "C" void kernel_launch(void* const* d_in, const int* in_sizes, int n_in,
                              void* d_out, int out_size, void* d_ws, size_t ws_size,
                              hipStream_t stream){
  (void)in_sizes; (void)n_in; (void)out_size;
  const float* xyz    = (const float*)d_in[0];
  const float* points = (const float*)d_in[1];
  const float* W0 = (const float*)d_in[2];
  const float* g0 = (const float*)d_in[3];
  const float* b0 = (const float*)d_in[4];
  const float* W1 = (const float*)d_in[5];
  const float* g1 = (const float*)d_in[6];
  const float* b1 = (const float*)d_in[7];
  const float* W2 = (const float*)d_in[8];
  const float* g2 = (const float*)d_in[9];
  const float* b2 = (const float*)d_in[10];

  float* out = (float*)d_out;
  float* o_newxyz = out;
  float* o_newpts = out + (size_t)B_ * M_ * 3;
  float* o_gind   = out + (size_t)B_ * M_ * 3 + (size_t)B_ * M_ * 128;

  char* ws = (char*)d_ws;
  int*   gi   = (int*)(ws + 0);                         // 2 MB
  float* part = (float*)(ws + (2u << 20));              // 4 MB
  float* bn0  = (float*)(ws + (6u << 20));
  float* bn1  = (float*)(ws + (6u << 20) + 1024);
  float* bn2  = (float*)(ws + (6u << 20) + 2048);
  unsigned short* h0 = (unsigned short*)(ws + (8u << 20));                    // 64 MB
  unsigned short* h1 = (unsigned short*)(ws + (8u << 20) + 67108864ull);      // 64 MB
  unsigned short* h2 = (unsigned short*)(ws + (8u << 20) + 2ull * 67108864ull); // 128 MB
  const bool full = ws_size >= ((8ull << 20) + 2ull * 67108864ull + 134217728ull);

  fps_kernel<<<16, 256, 0, stream>>>(xyz, o_newxyz);
  ballq_kernel<<<4096, 256, 0, stream>>>(xyz, o_newxyz, gi, o_gind);

  mlp_pass<67, 64, 0, 0><<<4096, 256, 0, stream>>>(xyz, points, o_newxyz, gi,
      nullptr, nullptr, W0, h0, part, nullptr, nullptr);
  reduce_stats<<<64, 256, 0, stream>>>(part, g0, b0, bn0, 64);

  mlp_pass<64, 64, 1, 0><<<4096, 256, 0, stream>>>(xyz, points, o_newxyz, gi,
      h0, bn0, W1, h1, part, nullptr, nullptr);
  reduce_stats<<<64, 256, 0, stream>>>(part, g1, b1, bn1, 64);

  if (full){
    mlp_pass<64, 128, 1, 0><<<4096, 256, 0, stream>>>(xyz, points, o_newxyz, gi,
        h1, bn1, W2, h2, part, nullptr, nullptr);
    reduce_stats<<<128, 256, 0, stream>>>(part, g2, b2, bn2, 128);
    maxpool_kernel<<<16384, 128, 0, stream>>>(h2, bn2, o_newpts);
  } else {
    mlp_pass<64, 128, 1, 1><<<4096, 256, 0, stream>>>(xyz, points, o_newxyz, gi,
        h1, bn1, W2, nullptr, part, nullptr, nullptr);
    reduce_stats<<<128, 256, 0, stream>>>(part, g2, b2, bn2, 128);
    mlp_pass<64, 128, 1, 2><<<4096, 256, 0, stream>>>(xyz, points, o_newxyz, gi,
        h1, bn1, W2, nullptr, nullptr, bn2, o_newpts);
  }
}

// Round 7
// 1214.908 us; speedup vs baseline: 1.2383x; 1.0495x over previous
//
#include <hip/hip_runtime.h>
#include <hip/hip_bf16.h>
#include <cstdint>

#define B_ 16
#define N_ 4096
#define CPTS_ 64
#define M_ 1024
#define K_ 32

using ushort8 = __attribute__((ext_vector_type(8))) unsigned short;

static __device__ __forceinline__ unsigned f2bf(float x){
  unsigned u = __float_as_uint(x);
  return (u + 0x7fffu + ((u >> 16) & 1u)) >> 16;   // RTNE
}
static __device__ __forceinline__ float bf2f(unsigned short u){
  return __uint_as_float(((unsigned)u) << 16);
}

// DPP max step: v = max(v, dpp_shift(v)). Values are >= 0 so 0-fill is identity.
#define DPPMAX(v, ctrl)                                                        \
  do {                                                                         \
    int _t = __builtin_amdgcn_update_dpp(0, __float_as_int(v), (ctrl), 0xf,    \
                                         0xf, true);                           \
    (v) = fmaxf((v), __int_as_float(_t));                                      \
  } while (0)

// One distance update, all indices compile-time constant (named float4 comps).
// Arithmetic identical to the passing R1-R6 versions (contract off, order kept).
#define STEP(MD, PX, PY, PZ, C, J)                                             \
  { float dx = PX.C - cx, dy = PY.C - cy, dz = PZ.C - cz;                      \
    float d = dx * dx; d = d + dy * dy; d = d + dz * dz;                       \
    float nm = fminf(MD.C, d); MD.C = nm;                                      \
    if (nm > bv){ bv = nm; bj = (J); } }
#define STEP4(MD, PX, PY, PZ, J0)                                              \
  STEP(MD, PX, PY, PZ, x, J0)                                                  \
  STEP(MD, PX, PY, PZ, y, (J0) + 1)                                            \
  STEP(MD, PX, PY, PZ, z, (J0) + 2)                                            \
  STEP(MD, PX, PY, PZ, w, (J0) + 3)

// ---------------- FPS: one block per batch, sequential argmax chain ---------
// R7: 512 threads / 8 pts per lane (halves per-wave update issue on the
// critical path); cross-wave exchange carries ONLY the packed u64 — centroid
// coords are re-read via broadcast LDS load xs[far] after the tree (removes
// the pre-barrier winner coord fetch + 12 coord slot reads + select chain).
__global__ __launch_bounds__(512, 1) void fps_kernel(const float* __restrict__ xyz,
                                                     float* __restrict__ newxyz){
#pragma clang fp contract(off)
  __shared__ float xs[N_], ys[N_], zs[N_];
  __shared__ int inds_s[M_];
  __shared__ unsigned long long sv_[2][8];
  const int b = blockIdx.x, tid = threadIdx.x;
  const int lane = tid & 63, wv = tid >> 6;
  const float* xb = xyz + (size_t)b * N_ * 3;
  for (int i = tid; i < N_ * 3; i += 512){
    float v = xb[i];
    int n = i / 3, c = i - n * 3;
    if (c == 0) xs[n] = v; else if (c == 1) ys[n] = v; else zs[n] = v;
  }
  __syncthreads();
  // per-lane points: n = tid*8 + j  (wave w owns [w*512, w*512+512))
  const float4 px0 = *reinterpret_cast<const float4*>(&xs[tid * 8 + 0]);
  const float4 px1 = *reinterpret_cast<const float4*>(&xs[tid * 8 + 4]);
  const float4 py0 = *reinterpret_cast<const float4*>(&ys[tid * 8 + 0]);
  const float4 py1 = *reinterpret_cast<const float4*>(&ys[tid * 8 + 4]);
  const float4 pz0 = *reinterpret_cast<const float4*>(&zs[tid * 8 + 0]);
  const float4 pz1 = *reinterpret_cast<const float4*>(&zs[tid * 8 + 4]);
  float4 md0 = make_float4(1e10f, 1e10f, 1e10f, 1e10f);
  float4 md1 = md0;
  int far = 0;
  float cx = xs[0], cy = ys[0], cz = zs[0];
  for (int m = 0; m < M_; ++m){
    if (tid == 0) inds_s[m] = far;
    float bv = -1.0f; int bj = 0;
    STEP4(md0, px0, py0, pz0, 0)
    STEP4(md1, px1, py1, pz1, 4)
    // in-wave max via DPP (VALU, no LDS): result in lane 63
    float wm = bv;
    DPPMAX(wm, 0x111);  // row_shr:1
    DPPMAX(wm, 0x112);  // row_shr:2
    DPPMAX(wm, 0x114);  // row_shr:4
    DPPMAX(wm, 0x118);  // row_shr:8
    DPPMAX(wm, 0x142);  // row_bcast:15
    DPPMAX(wm, 0x143);  // row_bcast:31
    const float wmax = __int_as_float(
        __builtin_amdgcn_readlane(__float_as_int(wm), 63));
    // lowest tied lane = smallest n (lane ascending == n ascending per wave)
    unsigned long long tied = __ballot(bv == wmax);
    const int winlane = (int)__builtin_ctzll(tied);
    const int sl = m & 1;
    if (lane == winlane){
      int wn = tid * 8 + bj;
      sv_[sl][wv] = ((unsigned long long)__float_as_uint(wmax) << 32)
                  | (unsigned)(4095 - wn);     // (4095-n): smaller n wins on tie
    }
    __syncthreads();
    // 8-slot max tree; all pk distinct (distinct indices) => total order
    unsigned long long p0 = sv_[sl][0], p1 = sv_[sl][1], p2 = sv_[sl][2], p3 = sv_[sl][3];
    unsigned long long p4 = sv_[sl][4], p5 = sv_[sl][5], p6 = sv_[sl][6], p7 = sv_[sl][7];
    if (p1 > p0) p0 = p1;
    if (p3 > p2) p2 = p3;
    if (p5 > p4) p4 = p5;
    if (p7 > p6) p6 = p7;
    if (p2 > p0) p0 = p2;
    if (p6 > p4) p4 = p6;
    if (p4 > p0) p0 = p4;
    far = 4095 - (int)(p0 & 0xffffffffu);
    cx = xs[far]; cy = ys[far]; cz = zs[far];   // broadcast LDS reads
  }
  __syncthreads();
  for (int t = tid; t < M_; t += 512){
    int id = inds_s[t];
    size_t o = ((size_t)b * M_ + t) * 3;
    newxyz[o] = xs[id]; newxyz[o + 1] = ys[id]; newxyz[o + 2] = zs[id];
  }
}

// ---------------- Ball query: one wave per centroid ------------------------
// fmaf chains match XLA's ffp-contract codegen (R2, exact).
__global__ __launch_bounds__(256) void ballq_kernel(const float* __restrict__ xyz,
                                                    const float* __restrict__ newxyz,
                                                    int* __restrict__ gi,
                                                    float* __restrict__ gif){
  const int gw = (blockIdx.x * 256 + threadIdx.x) >> 6;
  const int lane = threadIdx.x & 63;
  const int b = gw >> 10, m = gw & 1023;
  const float* xb = xyz + (size_t)b * N_ * 3;
  const size_t no = (size_t)b * M_ + m;
  const float cx = newxyz[no * 3], cy = newxyz[no * 3 + 1], cz = newxyz[no * 3 + 2];
  const float sm = fmaf(cz, cz, fmaf(cy, cy, cx * cx));
  int total = 0, first_idx = 0; bool havef = false;
  int*   gd = gi  + no * K_;
  float* fd = gif + no * K_;
  for (int ch = 0; ch < 64 && total < K_; ++ch){
    const int n = ch * 64 + lane;
    const float x = xb[n * 3], y = xb[n * 3 + 1], z = xb[n * 3 + 2];
    const float sn = fmaf(z, z, fmaf(y, y, x * x));
    const float dt = fmaf(z, cz, fmaf(y, cy, x * cx));
    float d2 = (sm + sn) - 2.0f * dt;                 // ref: |a|^2+|b|^2-2ab
    float dist = sqrtf(fmaxf(d2, 0.0f));
    bool pred = !(dist > 0.2f);
    unsigned long long mask = __ballot(pred);
    if (!havef && mask){ havef = true; first_idx = ch * 64 + (int)__builtin_ctzll(mask); }
    if (pred){
      int rank = total + (int)__popcll(mask & ((1ull << lane) - 1ull));
      if (rank < K_){ gd[rank] = n; fd[rank] = (float)n; }
    }
    total += (int)__popcll(mask);
  }
  if (total < K_ && lane >= total && lane < K_){ gd[lane] = first_idx; fd[lane] = (float)first_idx; }
}

// ---------------- MLP pass (gather / bn-in, store+stats / stats / maxpool) --
// MIN_: 0 = gather feats from xyz/points, 1 = read h_in (bf16) + BN + ReLU
// MOUT_: 0 = store h (bf16) + partial stats, 1 = partial stats only,
//        2 = BN + ReLU + max-pool over K -> out
template<int CIN, int COUT, int MIN_, int MOUT_>
__global__ __launch_bounds__(256) void mlp_pass(
    const float* __restrict__ xyz, const float* __restrict__ points,
    const float* __restrict__ newxyz, const int* __restrict__ gi,
    const unsigned short* __restrict__ hin, const float* __restrict__ bnin,
    const float* __restrict__ W,
    unsigned short* __restrict__ hout, float* __restrict__ part,
    const float* __restrict__ bncur, float* __restrict__ out)
{
  constexpr int OPT = COUT / 8;
  static_assert(OPT % 4 == 0, "OPT");
  __shared__ __align__(16) float Wt[CIN][COUT];
  __shared__ __align__(16) float ft[CIN][128];
  const int tid = threadIdx.x, blk = blockIdx.x;
  const size_t s0 = (size_t)blk * 128;

  for (int i = tid; i < CIN * COUT; i += 256){
    int o = i / CIN, c = i - o * CIN;
    Wt[c][o] = W[i];
  }

  if constexpr (MIN_ == 0){
    __shared__ int gidx[128];
    __shared__ float nx[4][3];
    const int b  = (int)(s0 >> 15);                 // 32768 samples per batch
    const int m0 = ((int)(s0 & 32767)) >> 5;        // 4 m's per block
    if (tid < 128) gidx[tid] = gi[(size_t)b * 32768 + (size_t)m0 * K_ + tid];
    if (tid < 12){
      int mi = tid / 3, c = tid - mi * 3;
      nx[mi][c] = newxyz[((size_t)b * M_ + m0 + mi) * 3 + c];
    }
    __syncthreads();
    const int sl = tid >> 1, half = tid & 1;
    const int g = gidx[sl];
    const float* ps = points + ((size_t)b * N_ + g) * CPTS_ + half * 32;
    #pragma unroll
    for (int j = 0; j < 8; ++j){
      float4 v = *reinterpret_cast<const float4*>(ps + j * 4);
      int c = 3 + half * 32 + j * 4;
      ft[c][sl] = v.x; ft[c + 1][sl] = v.y; ft[c + 2][sl] = v.z; ft[c + 3][sl] = v.w;
    }
    if (half == 0){
      const float* xp = xyz + ((size_t)b * N_ + g) * 3;
      const int mi = sl >> 5;
      ft[0][sl] = xp[0] - nx[mi][0];
      ft[1][sl] = xp[1] - nx[mi][1];
      ft[2][sl] = xp[2] - nx[mi][2];
    }
  } else {
    const int sl = tid >> 1, c0 = (tid & 1) * 32;
    const unsigned short* hp = hin + (s0 + sl) * CIN + c0;
    #pragma unroll
    for (int j = 0; j < 4; ++j){
      ushort8 raw = *reinterpret_cast<const ushort8*>(hp + j * 8);
      #pragma unroll
      for (int e = 0; e < 8; ++e){
        int c = c0 + j * 8 + e;
        float h = bf2f(raw[e]);
        float f = h * bnin[c] + bnin[CIN + c];
        ft[c][sl] = fmaxf(f, 0.0f);
      }
    }
  }
  __syncthreads();

  const int sg = tid & 31, og = tid >> 5;
  float acc[4][OPT];
  #pragma unroll
  for (int i = 0; i < 4; ++i)
    #pragma unroll
    for (int o = 0; o < OPT; ++o) acc[i][o] = 0.0f;

  #pragma unroll 2
  for (int c = 0; c < CIN; ++c){
    float4 f = *reinterpret_cast<const float4*>(&ft[c][sg * 4]);
    float4 w[OPT / 4];
    #pragma unroll
    for (int j = 0; j < OPT / 4; ++j)
      w[j] = *reinterpret_cast<const float4*>(&Wt[c][og * OPT + j * 4]);
    const float fv[4] = {f.x, f.y, f.z, f.w};
    #pragma unroll
    for (int i = 0; i < 4; ++i){
      #pragma unroll
      for (int j = 0; j < OPT / 4; ++j){
        acc[i][j * 4 + 0] += fv[i] * w[j].x;
        acc[i][j * 4 + 1] += fv[i] * w[j].y;
        acc[i][j * 4 + 2] += fv[i] * w[j].z;
        acc[i][j * 4 + 3] += fv[i] * w[j].w;
      }
    }
  }

  if constexpr (MOUT_ == 0 || MOUT_ == 1){
    if constexpr (MOUT_ == 0){
      #pragma unroll
      for (int i = 0; i < 4; ++i){
        size_t s = s0 + sg * 4 + i;
        unsigned pk[OPT / 2];
        #pragma unroll
        for (int o = 0; o < OPT / 2; ++o)
          pk[o] = f2bf(acc[i][2 * o]) | (f2bf(acc[i][2 * o + 1]) << 16);
        uint4* dst = reinterpret_cast<uint4*>(hout + s * COUT + og * OPT);
        dst[0] = make_uint4(pk[0], pk[1], pk[2], pk[3]);
        if constexpr (OPT == 16) dst[1] = make_uint4(pk[4], pk[5], pk[6], pk[7]);
      }
    }
    float sv[OPT], sq[OPT];
    #pragma unroll
    for (int o = 0; o < OPT; ++o){
      float a0 = acc[0][o], a1 = acc[1][o], a2 = acc[2][o], a3 = acc[3][o];
      sv[o] = ((a0 + a1) + a2) + a3;
      sq[o] = ((a0 * a0 + a1 * a1) + a2 * a2) + a3 * a3;
    }
    #pragma unroll
    for (int off = 1; off < 32; off <<= 1){
      #pragma unroll
      for (int o = 0; o < OPT; ++o){
        sv[o] += __shfl_xor(sv[o], off);
        sq[o] += __shfl_xor(sq[o], off);
      }
    }
    if (sg == 0){
      #pragma unroll
      for (int o = 0; o < OPT; ++o){
        int ch = og * OPT + o;
        part[(size_t)(ch * 2) * 4096 + blk]     = sv[o];
        part[(size_t)(ch * 2 + 1) * 4096 + blk] = sq[o];
      }
    }
  } else {
    const int mloc = sg >> 3;
    float mx[OPT];
    #pragma unroll
    for (int o = 0; o < OPT; ++o){
      int ch = og * OPT + o;
      float a = bncur[ch], sh = bncur[COUT + ch];
      float v0 = fmaxf(acc[0][o] * a + sh, 0.0f);
      float v1 = fmaxf(acc[1][o] * a + sh, 0.0f);
      float v2 = fmaxf(acc[2][o] * a + sh, 0.0f);
      float v3 = fmaxf(acc[3][o] * a + sh, 0.0f);
      mx[o] = fmaxf(fmaxf(v0, v1), fmaxf(v2, v3));
    }
    #pragma unroll
    for (int off = 1; off < 8; off <<= 1)
      #pragma unroll
      for (int o = 0; o < OPT; ++o)
        mx[o] = fmaxf(mx[o], __shfl_xor(mx[o], off));
    if ((sg & 7) == 0){
      size_t mf = (s0 >> 5) + mloc;
      float* dst = out + mf * COUT + og * OPT;
      #pragma unroll
      for (int j = 0; j < OPT / 4; ++j)
        *reinterpret_cast<float4*>(dst + j * 4) =
            make_float4(mx[j * 4], mx[j * 4 + 1], mx[j * 4 + 2], mx[j * 4 + 3]);
    }
  }
}

// ---------------- BN stats reduce + scale/shift -----------------------------
__global__ __launch_bounds__(256) void reduce_stats(const float* __restrict__ part,
                                                    const float* __restrict__ g,
                                                    const float* __restrict__ bb,
                                                    float* __restrict__ bn, int cout){
  const int ch = blockIdx.x, tid = threadIdx.x;
  float s = 0.f, q = 0.f;
  const float* ps = part + (size_t)(ch * 2) * 4096;
  const float* pq = part + (size_t)(ch * 2 + 1) * 4096;
  for (int i = tid; i < 4096; i += 256){ s += ps[i]; q += pq[i]; }
  #pragma unroll
  for (int off = 1; off < 64; off <<= 1){ s += __shfl_xor(s, off); q += __shfl_xor(q, off); }
  __shared__ float as_[4], aq_[4];
  if ((tid & 63) == 0){ as_[tid >> 6] = s; aq_[tid >> 6] = q; }
  __syncthreads();
  if (tid == 0){
    float S = as_[0] + as_[1] + as_[2] + as_[3];
    float Q = aq_[0] + aq_[1] + aq_[2] + aq_[3];
    const float cnt = 524288.0f;
    float mean = S / cnt;
    float var  = Q / cnt - mean * mean;
    float sc = g[ch] / sqrtf(var + 1e-5f);
    bn[ch] = sc;
    bn[cout + ch] = bb[ch] - mean * sc;
  }
}

// ---------------- Max-pool from stored h2 (full-ws path) --------------------
__global__ __launch_bounds__(128) void maxpool_kernel(const unsigned short* __restrict__ h2,
                                                      const float* __restrict__ bn2,
                                                      float* __restrict__ out){
  const int mf = blockIdx.x, ch = threadIdx.x;
  const float a = bn2[ch], sh = bn2[128 + ch];
  const unsigned short* hp = h2 + (size_t)mf * 32 * 128 + ch;
  float mx = 0.0f;                       // ReLU outputs are >= 0
  #pragma unroll 8
  for (int k = 0; k < 32; ++k){
    float v = bf2f(hp[(size_t)k * 128]);
    mx = fmaxf(mx, fmaxf(v * a + sh, 0.0f));
  }
  out[(size_t)mf * 128 + ch] = mx;
}

extern "C" void kernel_launch(void* const* d_in, const int* in_sizes, int n_in,
                              void* d_out, int out_size, void* d_ws, size_t ws_size,
                              hipStream_t stream){
  (void)in_sizes; (void)n_in; (void)out_size;
  const float* xyz    = (const float*)d_in[0];
  const float* points = (const float*)d_in[1];
  const float* W0 = (const float*)d_in[2];
  const float* g0 = (const float*)d_in[3];
  const float* b0 = (const float*)d_in[4];
  const float* W1 = (const float*)d_in[5];
  const float* g1 = (const float*)d_in[6];
  const float* b1 = (const float*)d_in[7];
  const float* W2 = (const float*)d_in[8];
  const float* g2 = (const float*)d_in[9];
  const float* b2 = (const float*)d_in[10];

  float* out = (float*)d_out;
  float* o_newxyz = out;
  float* o_newpts = out + (size_t)B_ * M_ * 3;
  float* o_gind   = out + (size_t)B_ * M_ * 3 + (size_t)B_ * M_ * 128;

  char* ws = (char*)d_ws;
  int*   gi   = (int*)(ws + 0);                         // 2 MB
  float* part = (float*)(ws + (2u << 20));              // 4 MB
  float* bn0  = (float*)(ws + (6u << 20));
  float* bn1  = (float*)(ws + (6u << 20) + 1024);
  float* bn2  = (float*)(ws + (6u << 20) + 2048);
  unsigned short* h0 = (unsigned short*)(ws + (8u << 20));                    // 64 MB
  unsigned short* h1 = (unsigned short*)(ws + (8u << 20) + 67108864ull);      // 64 MB
  unsigned short* h2 = (unsigned short*)(ws + (8u << 20) + 2ull * 67108864ull); // 128 MB
  const bool full = ws_size >= ((8ull << 20) + 2ull * 67108864ull + 134217728ull);

  fps_kernel<<<16, 512, 0, stream>>>(xyz, o_newxyz);
  ballq_kernel<<<4096, 256, 0, stream>>>(xyz, o_newxyz, gi, o_gind);

  mlp_pass<67, 64, 0, 0><<<4096, 256, 0, stream>>>(xyz, points, o_newxyz, gi,
      nullptr, nullptr, W0, h0, part, nullptr, nullptr);
  reduce_stats<<<64, 256, 0, stream>>>(part, g0, b0, bn0, 64);

  mlp_pass<64, 64, 1, 0><<<4096, 256, 0, stream>>>(xyz, points, o_newxyz, gi,
      h0, bn0, W1, h1, part, nullptr, nullptr);
  reduce_stats<<<64, 256, 0, stream>>>(part, g1, b1, bn1, 64);

  if (full){
    mlp_pass<64, 128, 1, 0><<<4096, 256, 0, stream>>>(xyz, points, o_newxyz, gi,
        h1, bn1, W2, h2, part, nullptr, nullptr);
    reduce_stats<<<128, 256, 0, stream>>>(part, g2, b2, bn2, 128);
    maxpool_kernel<<<16384, 128, 0, stream>>>(h2, bn2, o_newpts);
  } else {
    mlp_pass<64, 128, 1, 1><<<4096, 256, 0, stream>>>(xyz, points, o_newxyz, gi,
        h1, bn1, W2, nullptr, part, nullptr, nullptr);
    reduce_stats<<<128, 256, 0, stream>>>(part, g2, b2, bn2, 128);
    mlp_pass<64, 128, 1, 2><<<4096, 256, 0, stream>>>(xyz, points, o_newxyz, gi,
        h1, bn1, W2, nullptr, nullptr, bn2, o_newpts);
  }
}